// Round 4
// baseline (679.462 us; speedup 1.0000x reference)
//
#include <hip/hip_runtime.h>

// OnlineReweightingLoss: N=1048576, C=64, S=8.
// out = sum_k ( sum_{i in key k} per_sample_i ) / count_k
//
// ONE kernel: 16 lanes/row (lane owns one float4), 16 rows/wave-iter via 4
// independent coalesced 1 KB dwordx4 loads. Row-sum via shfl_xor(16);
// target-owner lane accumulates (sum,count) into 512-bin LDS histogram;
// blocks flush via global atomics; LAST block (ticket) computes the final
// sum_k gsum/gcnt and writes out[0]. targets/subg loaded unconditionally
// (broadcast lines) to avoid serialized divergent VMEM round-trips.

#define NKEYS 512
typedef float v4f __attribute__((ext_vector_type(4)));

__device__ __forceinline__ float pick4(v4f v, int j) {
    float r = v.x;
    r = (j == 1) ? v.y : r;
    r = (j == 2) ? v.z : r;
    r = (j == 3) ? v.w : r;
    return r;
}

__device__ __forceinline__ float esum4(v4f v) {
    return __expf(v.x) + __expf(v.y) + __expf(v.z) + __expf(v.w);
}

__global__ __launch_bounds__(256)
void orl_fused_kernel(const float* __restrict__ logits,
                      const int* __restrict__ targets,
                      const int* __restrict__ subg,
                      float* __restrict__ gsum,          // [NKEYS]
                      unsigned int* __restrict__ gcnt,   // [NKEYS]
                      unsigned int* __restrict__ ticket, // [1]
                      float* __restrict__ out, int n) {
    __shared__ float        lsum[NKEYS];
    __shared__ unsigned int lcnt[NKEYS];
    for (int i = threadIdx.x; i < NKEYS; i += 256) { lsum[i] = 0.0f; lcnt[i] = 0u; }
    __syncthreads();

    const int lane = threadIdx.x & 63;
    const int q    = lane & 15;        // float4 index within row
    const int g    = lane >> 4;        // row within 4-row group
    const int wave = (blockIdx.x << 2) | (threadIdx.x >> 6);
    const int nwaves = gridDim.x << 2;

    int base = wave * 16;
    for (; base + 16 <= n; base += nwaves * 16) {
        const int r0 = base + g, r1 = base + 4 + g, r2 = base + 8 + g, r3 = base + 12 + g;
        // 4 independent fully-coalesced 1 KB loads issued before any use.
        const v4f v0 = *((const v4f*)(logits + (size_t)r0 * 64) + q);
        const v4f v1 = *((const v4f*)(logits + (size_t)r1 * 64) + q);
        const v4f v2 = *((const v4f*)(logits + (size_t)r2 * 64) + q);
        const v4f v3 = *((const v4f*)(logits + (size_t)r3 * 64) + q);
        // index loads hoisted out of the divergent blocks (broadcast lines)
        const int t0 = targets[r0], t1 = targets[r1], t2 = targets[r2], t3 = targets[r3];
        const int u0 = subg[r0],    u1 = subg[r1],    u2 = subg[r2],    u3 = subg[r3];

        float s0 = esum4(v0), s1 = esum4(v1), s2 = esum4(v2), s3 = esum4(v3);
        #pragma unroll
        for (int m = 1; m < 16; m <<= 1) {
            s0 += __shfl_xor(s0, m, 16);
            s1 += __shfl_xor(s1, m, 16);
            s2 += __shfl_xor(s2, m, 16);
            s3 += __shfl_xor(s3, m, 16);
        }
        if ((t0 >> 2) == q) {
            const float ps = __logf(s0) - pick4(v0, t0 & 3);
            atomicAdd(&lsum[t0 * 8 + u0], ps); atomicAdd(&lcnt[t0 * 8 + u0], 1u);
        }
        if ((t1 >> 2) == q) {
            const float ps = __logf(s1) - pick4(v1, t1 & 3);
            atomicAdd(&lsum[t1 * 8 + u1], ps); atomicAdd(&lcnt[t1 * 8 + u1], 1u);
        }
        if ((t2 >> 2) == q) {
            const float ps = __logf(s2) - pick4(v2, t2 & 3);
            atomicAdd(&lsum[t2 * 8 + u2], ps); atomicAdd(&lcnt[t2 * 8 + u2], 1u);
        }
        if ((t3 >> 2) == q) {
            const float ps = __logf(s3) - pick4(v3, t3 & 3);
            atomicAdd(&lsum[t3 * 8 + u3], ps); atomicAdd(&lcnt[t3 * 8 + u3], 1u);
        }
    }
    // generic-n tail (not taken for N=1M with this grid)
    for (int o = 0; o < 16; o += 4) {
        const int r = base + o + g;
        if (r < n) {
            const v4f v = *((const v4f*)(logits + (size_t)r * 64) + q);
            const int t = targets[r];
            float s = esum4(v);
            #pragma unroll
            for (int m = 1; m < 16; m <<= 1) s += __shfl_xor(s, m, 16);
            if ((t >> 2) == q) {
                const float ps = __logf(s) - pick4(v, t & 3);
                const int key = t * 8 + subg[r];
                atomicAdd(&lsum[key], ps); atomicAdd(&lcnt[key], 1u);
            }
        }
    }

    __syncthreads();
    for (int i = threadIdx.x; i < NKEYS; i += 256) {
        const unsigned int c = lcnt[i];
        if (c) {
            atomicAdd(&gsum[i], lsum[i]);
            atomicAdd(&gcnt[i], c);
        }
    }

    // ---- last-block-done final reduction (removes a second launch) ----
    __shared__ bool amLast;
    __threadfence();                       // flushes visible before ticket
    __syncthreads();
    if (threadIdx.x == 0)
        amLast = (atomicAdd(ticket, 1u) == gridDim.x - 1);
    __syncthreads();
    if (!amLast) return;

    float v = 0.0f;
    #pragma unroll
    for (int rep = 0; rep < 2; ++rep) {
        const int k = threadIdx.x + rep * 256;
        // agent-scope atomic loads: bypass potentially-stale L1 (cross-XCD)
        const unsigned int c = __hip_atomic_load(&gcnt[k], __ATOMIC_RELAXED,
                                                 __HIP_MEMORY_SCOPE_AGENT);
        const float s = __hip_atomic_load(&gsum[k], __ATOMIC_RELAXED,
                                          __HIP_MEMORY_SCOPE_AGENT);
        if (c) v += s / (float)c;
    }
    #pragma unroll
    for (int m = 32; m > 0; m >>= 1) v += __shfl_down(v, m, 64);
    __shared__ float wsum[4];
    if ((threadIdx.x & 63) == 0) wsum[threadIdx.x >> 6] = v;
    __syncthreads();
    if (threadIdx.x == 0)
        out[0] = wsum[0] + wsum[1] + wsum[2] + wsum[3];
}

extern "C" void kernel_launch(void* const* d_in, const int* in_sizes, int n_in,
                              void* d_out, int out_size, void* d_ws, size_t ws_size,
                              hipStream_t stream) {
    const float* logits  = (const float*)d_in[0];
    const int*   targets = (const int*)d_in[1];
    const int*   subg    = (const int*)d_in[2];
    const int n = in_sizes[1];
    float* out = (float*)d_out;

    float*        gsum   = (float*)d_ws;
    unsigned int* gcnt   = (unsigned int*)((char*)d_ws + NKEYS * sizeof(float));
    unsigned int* ticket = gcnt + NKEYS;

    // ws is poisoned to 0xAA before every call — zero the 4 KB + ticket.
    hipMemsetAsync(d_ws, 0, NKEYS * 8 + sizeof(unsigned int), stream);

    // 2048 blocks x 4 waves = 8192 waves (32/CU); 16 rows/wave-iter.
    orl_fused_kernel<<<2048, 256, 0, stream>>>(logits, targets, subg,
                                               gsum, gcnt, ticket, out, n);
}

// Round 5
// 373.217 us; speedup vs baseline: 1.8206x; 1.8206x over previous
//
#include <hip/hip_runtime.h>

// OnlineReweightingLoss: N=1048576, C=64, S=8.
// out = sum_k ( sum_{i in key k} per_sample_i ) / count_k
//
// Kernel A: 512 blocks x 256 thr. 16 lanes/row (lane owns one float4),
//   16 rows/wave-iter via 4 independent coalesced 1 KB nontemporal loads.
//   Row-sum via shfl_xor(16); owner lane accumulates into 512-bin LDS
//   histogram. Flush: plain coalesced stores to a PRIVATE per-block slice
//   (no global atomics, no fences — R3 showed agent fences + contended
//   atomics cost ~300 us).
// Kernel B: 1 block x 1024 thr reduces the 512 slices (2 MB, L2-resident)
//   and writes out[0]. No memsets needed: every partial slot is written.

#define NKEYS 512
#define NSLICES 512   // == kernel A grid size
typedef float v4f __attribute__((ext_vector_type(4)));

__device__ __forceinline__ float pick4(v4f v, int j) {
    float r = v.x;
    r = (j == 1) ? v.y : r;
    r = (j == 2) ? v.z : r;
    r = (j == 3) ? v.w : r;
    return r;
}

__device__ __forceinline__ float esum4(v4f v) {
    return __expf(v.x) + __expf(v.y) + __expf(v.z) + __expf(v.w);
}

__global__ __launch_bounds__(256)
void orl_hist_kernel(const float* __restrict__ logits,
                     const int* __restrict__ targets,
                     const int* __restrict__ subg,
                     float* __restrict__ psum,          // [NSLICES][NKEYS]
                     unsigned int* __restrict__ pcnt,   // [NSLICES][NKEYS]
                     int n) {
    __shared__ float        lsum[NKEYS];
    __shared__ unsigned int lcnt[NKEYS];
    for (int i = threadIdx.x; i < NKEYS; i += 256) { lsum[i] = 0.0f; lcnt[i] = 0u; }
    __syncthreads();

    const int lane = threadIdx.x & 63;
    const int q    = lane & 15;        // float4 index within row
    const int g    = lane >> 4;        // row within 4-row group
    const int wave = (blockIdx.x << 2) | (threadIdx.x >> 6);
    const int nwaves = gridDim.x << 2;

    int base = wave * 16;
    for (; base + 16 <= n; base += nwaves * 16) {
        const int r0 = base + g, r1 = base + 4 + g, r2 = base + 8 + g, r3 = base + 12 + g;
        // 4 independent fully-coalesced 1 KB loads; nontemporal (zero reuse).
        const v4f v0 = __builtin_nontemporal_load((const v4f*)(logits + (size_t)r0 * 64) + q);
        const v4f v1 = __builtin_nontemporal_load((const v4f*)(logits + (size_t)r1 * 64) + q);
        const v4f v2 = __builtin_nontemporal_load((const v4f*)(logits + (size_t)r2 * 64) + q);
        const v4f v3 = __builtin_nontemporal_load((const v4f*)(logits + (size_t)r3 * 64) + q);
        const int t0 = targets[r0], t1 = targets[r1], t2 = targets[r2], t3 = targets[r3];
        const int u0 = subg[r0],    u1 = subg[r1],    u2 = subg[r2],    u3 = subg[r3];

        float s0 = esum4(v0), s1 = esum4(v1), s2 = esum4(v2), s3 = esum4(v3);
        #pragma unroll
        for (int m = 1; m < 16; m <<= 1) {
            s0 += __shfl_xor(s0, m, 16);
            s1 += __shfl_xor(s1, m, 16);
            s2 += __shfl_xor(s2, m, 16);
            s3 += __shfl_xor(s3, m, 16);
        }
        if ((t0 >> 2) == q) {
            const float ps = __logf(s0) - pick4(v0, t0 & 3);
            atomicAdd(&lsum[t0 * 8 + u0], ps); atomicAdd(&lcnt[t0 * 8 + u0], 1u);
        }
        if ((t1 >> 2) == q) {
            const float ps = __logf(s1) - pick4(v1, t1 & 3);
            atomicAdd(&lsum[t1 * 8 + u1], ps); atomicAdd(&lcnt[t1 * 8 + u1], 1u);
        }
        if ((t2 >> 2) == q) {
            const float ps = __logf(s2) - pick4(v2, t2 & 3);
            atomicAdd(&lsum[t2 * 8 + u2], ps); atomicAdd(&lcnt[t2 * 8 + u2], 1u);
        }
        if ((t3 >> 2) == q) {
            const float ps = __logf(s3) - pick4(v3, t3 & 3);
            atomicAdd(&lsum[t3 * 8 + u3], ps); atomicAdd(&lcnt[t3 * 8 + u3], 1u);
        }
    }
    // generic-n tail (not taken for N=1M with this grid)
    for (int o = 0; o < 16; o += 4) {
        const int r = base + o + g;
        if (r < n) {
            const v4f v = *((const v4f*)(logits + (size_t)r * 64) + q);
            const int t = targets[r];
            float s = esum4(v);
            #pragma unroll
            for (int m = 1; m < 16; m <<= 1) s += __shfl_xor(s, m, 16);
            if ((t >> 2) == q) {
                const float ps = __logf(s) - pick4(v, t & 3);
                const int key = t * 8 + subg[r];
                atomicAdd(&lsum[key], ps); atomicAdd(&lcnt[key], 1u);
            }
        }
    }

    __syncthreads();
    // Private-slice flush: plain coalesced stores, ALL 512 bins (incl. zeros
    // — ws is poisoned, every slot must be written).
    const size_t sbase = (size_t)blockIdx.x * NKEYS;
    for (int i = threadIdx.x; i < NKEYS; i += 256) {
        psum[sbase + i] = lsum[i];
        pcnt[sbase + i] = lcnt[i];
    }
}

__global__ __launch_bounds__(1024)
void orl_reduce_kernel(const float* __restrict__ psum,
                       const unsigned int* __restrict__ pcnt,
                       float* __restrict__ out) {
    const int t = threadIdx.x;
    const int k = t & (NKEYS - 1);
    const int h = t >> 9;                    // 0 or 1: which half of slices
    float s = 0.0f; unsigned int c = 0u;
    const int b0 = h * (NSLICES / 2);
    #pragma unroll 8
    for (int b = b0; b < b0 + NSLICES / 2; ++b) {
        s += psum[(size_t)b * NKEYS + k];    // lanes coalesced across k
        c += pcnt[(size_t)b * NKEYS + k];
    }
    __shared__ float        s2[NKEYS];
    __shared__ unsigned int c2[NKEYS];
    if (h) { s2[k] = s; c2[k] = c; }
    __syncthreads();
    float v = 0.0f;
    if (!h) {
        const float S = s + s2[k];
        const unsigned int C = c + c2[k];
        v = C ? S / (float)C : 0.0f;
    }
    #pragma unroll
    for (int m = 32; m > 0; m >>= 1) v += __shfl_down(v, m, 64);
    __shared__ float wred[16];
    if ((t & 63) == 0) wred[t >> 6] = v;
    __syncthreads();
    if (t == 0) {
        float r = 0.0f;
        #pragma unroll
        for (int w = 0; w < 16; ++w) r += wred[w];
        out[0] = r;
    }
}

extern "C" void kernel_launch(void* const* d_in, const int* in_sizes, int n_in,
                              void* d_out, int out_size, void* d_ws, size_t ws_size,
                              hipStream_t stream) {
    const float* logits  = (const float*)d_in[0];
    const int*   targets = (const int*)d_in[1];
    const int*   subg    = (const int*)d_in[2];
    const int n = in_sizes[1];
    float* out = (float*)d_out;

    float*        psum = (float*)d_ws;                            // 1 MB
    unsigned int* pcnt = (unsigned int*)((char*)d_ws + (size_t)NSLICES * NKEYS * 4);

    // No memsets: kernel A writes every partial slot; kernel B writes out[0].
    orl_hist_kernel<<<NSLICES, 256, 0, stream>>>(logits, targets, subg, psum, pcnt, n);
    orl_reduce_kernel<<<1, 1024, 0, stream>>>(psum, pcnt, out);
}

// Round 6
// 361.021 us; speedup vs baseline: 1.8821x; 1.0338x over previous
//
#include <hip/hip_runtime.h>

// OnlineReweightingLoss: N=1048576, C=64, S=8.
// out = sum_k ( sum_{i in key k} per_sample_i ) / count_k
//
// Kernel A: 512 blocks x 256 thr. 16 lanes/row (lane owns one float4),
//   16 rows/wave-iter; lane's 4 rows are CONTIGUOUS (row = base+4g+j) so
//   targets/subg load as one int4 each (2 VMEM instrs vs 8). Logits via 4
//   independent nontemporal dwordx4 loads (16 lines each, fully coalesced).
//   Row-sum via shfl_xor(16); owner lane -> 512-bin LDS histogram; flush =
//   plain coalesced stores to private per-block slice (no global atomics).
// Kernel B: 64 blocks x 256 thr; block b reduces keys [8b,8b+8) across all
//   512 slices (L2-resident), one atomicAdd(out) per block (64 total).

#define NKEYS 512
#define NSLICES 512   // == kernel A grid size
typedef float v4f __attribute__((ext_vector_type(4)));

__device__ __forceinline__ float pick4(v4f v, int j) {
    float r = v.x;
    r = (j == 1) ? v.y : r;
    r = (j == 2) ? v.z : r;
    r = (j == 3) ? v.w : r;
    return r;
}

__device__ __forceinline__ float esum4(v4f v) {
    return __expf(v.x) + __expf(v.y) + __expf(v.z) + __expf(v.w);
}

__global__ __launch_bounds__(256)
void orl_hist_kernel(const float* __restrict__ logits,
                     const int* __restrict__ targets,
                     const int* __restrict__ subg,
                     float* __restrict__ psum,          // [NSLICES][NKEYS]
                     unsigned int* __restrict__ pcnt,   // [NSLICES][NKEYS]
                     int n) {
    __shared__ float        lsum[NKEYS];
    __shared__ unsigned int lcnt[NKEYS];
    for (int i = threadIdx.x; i < NKEYS; i += 256) { lsum[i] = 0.0f; lcnt[i] = 0u; }
    __syncthreads();

    const int lane = threadIdx.x & 63;
    const int q    = lane & 15;        // float4 index within row
    const int g    = lane >> 4;        // 4-row group within wave's 16 rows
    const int wave = (blockIdx.x << 2) | (threadIdx.x >> 6);
    const int nwaves = gridDim.x << 2;

    int base = wave * 16;
    for (; base + 16 <= n; base += nwaves * 16) {
        const int r0 = base + g * 4;   // this lane-group's 4 contiguous rows
        // one int4 each for 4 targets / 4 subgroups (was 8 scalar loads)
        const int4 t4 = *(const int4*)(targets + r0);
        const int4 u4 = *(const int4*)(subg + r0);
        // 4 independent dwordx4 loads, 64-B-line coalesced; nontemporal.
        const float* rowp = logits + (size_t)r0 * 64 + q * 4;
        const v4f v0 = __builtin_nontemporal_load((const v4f*)(rowp));
        const v4f v1 = __builtin_nontemporal_load((const v4f*)(rowp + 64));
        const v4f v2 = __builtin_nontemporal_load((const v4f*)(rowp + 128));
        const v4f v3 = __builtin_nontemporal_load((const v4f*)(rowp + 192));

        float s0 = esum4(v0), s1 = esum4(v1), s2 = esum4(v2), s3 = esum4(v3);
        // xor-reduce over the 16 q-lanes sharing each row
        #pragma unroll
        for (int m = 1; m < 16; m <<= 1) {
            s0 += __shfl_xor(s0, m, 16);
            s1 += __shfl_xor(s1, m, 16);
            s2 += __shfl_xor(s2, m, 16);
            s3 += __shfl_xor(s3, m, 16);
        }
        if ((t4.x >> 2) == q) {
            const float ps = __logf(s0) - pick4(v0, t4.x & 3);
            atomicAdd(&lsum[t4.x * 8 + u4.x], ps); atomicAdd(&lcnt[t4.x * 8 + u4.x], 1u);
        }
        if ((t4.y >> 2) == q) {
            const float ps = __logf(s1) - pick4(v1, t4.y & 3);
            atomicAdd(&lsum[t4.y * 8 + u4.y], ps); atomicAdd(&lcnt[t4.y * 8 + u4.y], 1u);
        }
        if ((t4.z >> 2) == q) {
            const float ps = __logf(s2) - pick4(v2, t4.z & 3);
            atomicAdd(&lsum[t4.z * 8 + u4.z], ps); atomicAdd(&lcnt[t4.z * 8 + u4.z], 1u);
        }
        if ((t4.w >> 2) == q) {
            const float ps = __logf(s3) - pick4(v3, t4.w & 3);
            atomicAdd(&lsum[t4.w * 8 + u4.w], ps); atomicAdd(&lcnt[t4.w * 8 + u4.w], 1u);
        }
    }
    // generic-n tail (not taken for N=1M with this grid)
    for (int o = 0; o < 4; ++o) {
        const int r = base + g * 4 + o;
        if (r < n) {
            const v4f v = *((const v4f*)(logits + (size_t)r * 64) + q);
            const int t = targets[r];
            float s = esum4(v);
            #pragma unroll
            for (int m = 1; m < 16; m <<= 1) s += __shfl_xor(s, m, 16);
            if ((t >> 2) == q) {
                const float ps = __logf(s) - pick4(v, t & 3);
                const int key = t * 8 + subg[r];
                atomicAdd(&lsum[key], ps); atomicAdd(&lcnt[key], 1u);
            }
        }
    }

    __syncthreads();
    // Private-slice flush: plain coalesced stores, all 512 bins.
    const size_t sbase = (size_t)blockIdx.x * NKEYS;
    for (int i = threadIdx.x; i < NKEYS; i += 256) {
        psum[sbase + i] = lsum[i];
        pcnt[sbase + i] = lcnt[i];
    }
}

__global__ __launch_bounds__(256)
void orl_reduce_kernel(const float* __restrict__ psum,
                       const unsigned int* __restrict__ pcnt,
                       float* __restrict__ out) {
    const int kk  = threadIdx.x & 7;          // key within this block's 8
    const int sl  = threadIdx.x >> 3;         // 32 slice-lanes
    const int key = (blockIdx.x << 3) | kk;
    float s = 0.0f; unsigned int c = 0u;
    #pragma unroll 4
    for (int b = sl; b < NSLICES; b += 32) {
        s += psum[(size_t)b * NKEYS + key];
        c += pcnt[(size_t)b * NKEYS + key];
    }
    // reduce over lanes with the same kk inside the wave (xor 8,16,32)
    #pragma unroll
    for (int m = 8; m < 64; m <<= 1) {
        s += __shfl_xor(s, m, 64);
        c += __shfl_xor(c, m, 64);
    }
    __shared__ float        ls[4][8];
    __shared__ unsigned int lc[4][8];
    const int w = threadIdx.x >> 6;
    if ((threadIdx.x & 63) < 8) { ls[w][kk] = s; lc[w][kk] = c; }
    __syncthreads();
    if (threadIdx.x < 8) {
        const float        S = ls[0][kk] + ls[1][kk] + ls[2][kk] + ls[3][kk];
        const unsigned int C = lc[0][kk] + lc[1][kk] + lc[2][kk] + lc[3][kk];
        float v = C ? S / (float)C : 0.0f;
        #pragma unroll
        for (int m = 1; m < 8; m <<= 1) v += __shfl_xor(v, m, 8);
        if (threadIdx.x == 0) atomicAdd(out, v);   // 64 uncontended adds
    }
}

extern "C" void kernel_launch(void* const* d_in, const int* in_sizes, int n_in,
                              void* d_out, int out_size, void* d_ws, size_t ws_size,
                              hipStream_t stream) {
    const float* logits  = (const float*)d_in[0];
    const int*   targets = (const int*)d_in[1];
    const int*   subg    = (const int*)d_in[2];
    const int n = in_sizes[1];
    float* out = (float*)d_out;

    float*        psum = (float*)d_ws;                            // 1 MB
    unsigned int* pcnt = (unsigned int*)((char*)d_ws + (size_t)NSLICES * NKEYS * 4);

    hipMemsetAsync(out, 0, sizeof(float), stream);  // atomic target
    orl_hist_kernel<<<NSLICES, 256, 0, stream>>>(logits, targets, subg, psum, pcnt, n);
    orl_reduce_kernel<<<64, 256, 0, stream>>>(psum, pcnt, out);
}